// Round 1
// baseline (3414.596 us; speedup 1.0000x reference)
//
#include <hip/hip_runtime.h>
#include <math.h>

// ---------------------------------------------------------------------------
// Denoiser: normalize -> batched masked NNLS (FISTA, 500 it) -> BrainNetCNN
// All fp32. MI355X (gfx950). No fp32 MFMA exists -> FISTA runs on vector ALU.
// Design notes:
//  - FISTA: grad[j,m] = sum_n Y[j,n] * G[n,m]  (G symmetric), per-batch G in
//    LDS, Y kept in a transposed LDS tile Yt[n][j_local] so the inner loop is
//    1x b128 (Y) + 3x b64 (G) conflict-free reads + 24 FMAs per thread.
//  - grid 64 batches x 6 j-blocks of 16; block = 64 threads (one wave ->
//    __syncthreads is cheap, no inter-wave races).
//  - Padding M=90 -> 96 is self-consistent: padded G/C are zero so padded
//    state provably stays zero.
// ---------------------------------------------------------------------------

#define B_ 64
#define M_ 90
#define T_ 187
#define MP 96
#define NNLS_ITERS 500
#define POWER_ITERS 50
#define NEG_SLOPE 0.33f

#define MT_ (M_ * T_)                 // 16830
#define X0_OFF 0
#define A_OFF (B_ * MT_)              // 1077120
#define CLS_OFF (A_OFF + B_ * M_ * M_)// 1595520

// workspace layout (float offsets)
#define WS_G 0
#define WS_C (B_ * MP * MP)           // 589824
#define WS_STEP (2 * B_ * MP * MP)    // 1179648
#define WS_W3R (WS_STEP + B_)         // 1179712
#define WS_W4R (WS_W3R + 16 * 8 * M_) // 1191232
// total floats: 1202752 (~4.81 MB) -- well under typical ws_size

__device__ __forceinline__ float leaky(float x) {
    return x >= 0.f ? x : NEG_SLOPE * x;
}

// ---------------------------------------------------------------------------
// Kernel 1: per-batch mean / absmax -> x0_pred into d_out[X0_OFF..]
// ---------------------------------------------------------------------------
__global__ __launch_bounds__(256) void k_norm(const float* __restrict__ x0,
                                              float* __restrict__ out) {
    int b = blockIdx.x, tid = threadIdx.x;
    const float* x = x0 + b * MT_;
    float s = 0.f, mx = 0.f;
    for (int i = tid; i < MT_; i += 256) {
        float v = x[i];
        s += v;
        mx = fmaxf(mx, fabsf(v));
    }
    __shared__ float rs[256], rm[256];
    rs[tid] = s; rm[tid] = mx;
    __syncthreads();
    for (int st = 128; st > 0; st >>= 1) {
        if (tid < st) {
            rs[tid] += rs[tid + st];
            rm[tid] = fmaxf(rm[tid], rm[tid + st]);
        }
        __syncthreads();
    }
    float mean = rs[0] / (float)MT_;
    float mv = rm[0];
    float* o = out + X0_OFF + b * MT_;
    for (int i = tid; i < MT_; i += 256) {
        o[i] = (x[i] - mean) / mv;
    }
}

// ---------------------------------------------------------------------------
// Kernel 2: G[b][m][n] = dot(P_n, P_m); C[b][j][m] = dot(R_j, P_m).
// P rows cached in L1/L2 (67 KB/batch, L2-resident). Padded region zeroed.
// ---------------------------------------------------------------------------
__global__ __launch_bounds__(256) void k_gc(const float* __restrict__ out_x0,
                                            const float* __restrict__ rawx,
                                            float* __restrict__ ws) {
    int b = blockIdx.x, tid = threadIdx.x;
    const float* P = out_x0 + X0_OFF + b * MT_;
    const float* R = rawx + b * MT_;
    float* G = ws + WS_G + b * MP * MP;
    float* C = ws + WS_C + b * MP * MP;
    for (int idx = tid; idx < MP * MP; idx += 256) {
        int n = idx % MP;       // varies per lane (strided row reads, L1/L2)
        int m = idx / MP;       // ~uniform across a wave (broadcast row)
        float g = 0.f, c = 0.f;
        if (n < M_ && m < M_) {
            const float* pm = P + m * T_;
            const float* pn = P + n * T_;
            const float* rn = R + n * T_;
#pragma unroll 4
            for (int t = 0; t < T_; ++t) {
                float v = pm[t];
                g = fmaf(pn[t], v, g);
                c = fmaf(rn[t], v, c);
            }
        }
        G[m * MP + n] = g;      // symmetric: dot(P_n,P_m) == G[m][n]
        C[n * MP + m] = c;      // C[j=n][m]
    }
}

// ---------------------------------------------------------------------------
// Kernel 3: repack cnn3_w/cnn4_w from [o][c][hw] to [(c*90+hw)*16 + o]
// so the CNN kernel can do float4 reads over o.
// ---------------------------------------------------------------------------
__global__ __launch_bounds__(256) void k_prepack(const float* __restrict__ w3,
                                                 const float* __restrict__ w4,
                                                 float* __restrict__ ws) {
    int tid = threadIdx.x + blockIdx.x * 256;
    for (int i = tid; i < 16 * 8 * M_; i += 512) {
        int o = i & 15;
        int cw = i >> 4;
        int c = cw / M_;
        int w = cw % M_;
        ws[WS_W3R + i] = w3[(o * 8 + c) * M_ + w];
        ws[WS_W4R + i] = w4[(o * 8 + c) * M_ + w];
    }
}

// ---------------------------------------------------------------------------
// Kernel 4: power iteration (50 it) -> step[b] = 1 / (v^T G v * 1.01 + 1e-8)
// ---------------------------------------------------------------------------
__global__ __launch_bounds__(128) void k_power(float* __restrict__ ws) {
    int b = blockIdx.x, tid = threadIdx.x;
    const float* G = ws + WS_G + b * MP * MP;
    __shared__ float Gp[M_][91];   // stride 91: (91m+n)%32 bijective -> no conflicts
    __shared__ float v[M_];
    __shared__ float red[128];
    for (int i = tid; i < M_ * M_; i += 128) {
        int r = i / M_, c = i % M_;
        Gp[r][c] = G[r * MP + c];
    }
    if (tid < M_) v[tid] = 1.f;
    __syncthreads();
    for (int it = 0; it < POWER_ITERS; ++it) {
        float s = 0.f;
        if (tid < M_) {
#pragma unroll 4
            for (int n = 0; n < M_; ++n) s = fmaf(Gp[tid][n], v[n], s);
        }
        red[tid] = (tid < M_) ? s * s : 0.f;
        __syncthreads();
        for (int st = 64; st > 0; st >>= 1) {
            if (tid < st) red[tid] += red[tid + st];
            __syncthreads();
        }
        float nrm = sqrtf(red[0]);
        if (tid < M_) v[tid] = s / (nrm + 1e-12f);
        __syncthreads();
    }
    float s = 0.f;
    if (tid < M_) {
#pragma unroll 4
        for (int n = 0; n < M_; ++n) s = fmaf(Gp[tid][n], v[n], s);
        s *= v[tid];
    }
    red[tid] = (tid < M_) ? s : 0.f;
    __syncthreads();
    for (int st = 64; st > 0; st >>= 1) {
        if (tid < st) red[tid] += red[tid + st];
        __syncthreads();
    }
    if (tid == 0) {
        float L = red[0] * 1.01f + 1e-8f;
        ws[WS_STEP + b] = 1.f / L;
    }
}

// ---------------------------------------------------------------------------
// Kernel 5: FISTA, 500 iterations. One wave per block; block = (batch, j-block
// of 16). State (w, y, C-tile) in registers; G + transposed Y in LDS.
// ---------------------------------------------------------------------------
#define JB 16
#define TJ 4
#define TM 6
#define YT_STRIDE 20   // pad 16 -> 20: write quad-window (6mt+5d+jt)&7 spreads banks

__global__ __launch_bounds__(64) void k_fista(const float* __restrict__ ws,
                                              float* __restrict__ out) {
    int b = blockIdx.y;
    int j0 = blockIdx.x * JB;
    int tid = threadIdx.x;
    int mt = tid & 15;   // 0..15 -> m range mt*6..mt*6+5
    int jt = tid >> 4;   // 0..3  -> j-local range jt*4..jt*4+3

    const float* Gg = ws + WS_G + b * MP * MP;
    const float* Cg = ws + WS_C + b * MP * MP;
    float step = ws[WS_STEP + b];

    __shared__ float Gl[MP * MP];        // 36864 B, [n][m] row-major
    __shared__ float Yt[MP * YT_STRIDE]; // 7680 B,  [n][j_local]

    {
        const float4* g4 = (const float4*)Gg;
        float4* G4 = (float4*)Gl;
        for (int i = tid; i < MP * MP / 4; i += 64) G4[i] = g4[i];
    }
    for (int i = tid; i < MP * YT_STRIDE; i += 64) Yt[i] = 0.f;

    float c[TJ][TM], w[TJ][TM], y[TJ][TM];
#pragma unroll
    for (int a = 0; a < TJ; ++a)
#pragma unroll
        for (int d = 0; d < TM; ++d) {
            c[a][d] = Cg[(j0 + jt * TJ + a) * MP + mt * TM + d];
            w[a][d] = 0.f;
            y[a][d] = 0.f;
        }

    float t = 1.f;
    __syncthreads();

    const float* gp = Gl + mt * TM;
    const float* yp = Yt + jt * TJ;

    for (int it = 0; it < NNLS_ITERS; ++it) {
        float acc[TJ][TM];
#pragma unroll
        for (int a = 0; a < TJ; ++a)
#pragma unroll
            for (int d = 0; d < TM; ++d) acc[a][d] = 0.f;

#pragma unroll 4
        for (int n = 0; n < MP; ++n) {
            float4 yv = *(const float4*)(yp + n * YT_STRIDE);
            float2 ga = *(const float2*)(gp + n * MP);
            float2 gb = *(const float2*)(gp + n * MP + 2);
            float2 gc2 = *(const float2*)(gp + n * MP + 4);
            float yr[TJ] = {yv.x, yv.y, yv.z, yv.w};
#pragma unroll
            for (int a = 0; a < TJ; ++a) {
                acc[a][0] = fmaf(yr[a], ga.x, acc[a][0]);
                acc[a][1] = fmaf(yr[a], ga.y, acc[a][1]);
                acc[a][2] = fmaf(yr[a], gb.x, acc[a][2]);
                acc[a][3] = fmaf(yr[a], gb.y, acc[a][3]);
                acc[a][4] = fmaf(yr[a], gc2.x, acc[a][4]);
                acc[a][5] = fmaf(yr[a], gc2.y, acc[a][5]);
            }
        }

        float t1 = 0.5f * (1.f + sqrtf(1.f + 4.f * t * t));
        float coef = (t - 1.f) / t1;
        t = t1;

        __syncthreads();   // all Yt reads done before overwrite

#pragma unroll
        for (int a = 0; a < TJ; ++a) {
            int jg = j0 + jt * TJ + a;
#pragma unroll
            for (int d = 0; d < TM; ++d) {
                int mg = mt * TM + d;
                float gr = acc[a][d] - c[a][d];
                if (jg == mg) gr = 0.f;                      // mask
                float w1 = fmaxf(fmaf(-step, gr, y[a][d]), 0.f);
                float ynew = fmaf(coef, w1 - w[a][d], w1);
                w[a][d] = w1;
                y[a][d] = ynew;
            }
        }

#pragma unroll
        for (int d = 0; d < TM; ++d) {
            float4 val = make_float4(y[0][d], y[1][d], y[2][d], y[3][d]);
            *(float4*)(Yt + (mt * TM + d) * YT_STRIDE + jt * 4) = val;
        }
        __syncthreads();   // writes visible before next matmul
    }

    // store w -> A
#pragma unroll
    for (int a = 0; a < TJ; ++a) {
        int jg = j0 + jt * TJ + a;
        if (jg < M_) {
#pragma unroll
            for (int d = 0; d < TM; ++d) {
                int mg = mt * TM + d;
                if (mg < M_) out[A_OFF + b * M_ * M_ + jg * M_ + mg] = w[a][d];
            }
        }
    }
}

// ---------------------------------------------------------------------------
// Kernel 6: BrainNetCNN head, one block per batch.
// ---------------------------------------------------------------------------
__global__ __launch_bounds__(256) void k_cnn(
    const float* __restrict__ out_in, const float* __restrict__ ws,
    const float* __restrict__ c1w, const float* __restrict__ c1b,
    const float* __restrict__ c2w, const float* __restrict__ c2b,
    const float* __restrict__ c3b, const float* __restrict__ c4b,
    const float* __restrict__ e2nw, const float* __restrict__ e2nb,
    const float* __restrict__ n2gw, const float* __restrict__ n2gb,
    const float* __restrict__ d1w, const float* __restrict__ d1b,
    const float* __restrict__ d2w, const float* __restrict__ d2b,
    const float* __restrict__ d3w, const float* __restrict__ d3b,
    float* __restrict__ out) {
    int b = blockIdx.x, tid = threadIdx.x;
    __shared__ float A[M_][92];
    __shared__ float a1[8][92], b1[8][92];
    __shared__ float a2s[16][92], b2s[16][92];
    __shared__ float e2n[92], n2g[64], h1[128], h2[12];

    const float* Ag = out_in + A_OFF + b * M_ * M_;
    for (int i = tid; i < M_ * M_; i += 256) A[i / M_][i % M_] = Ag[i];
    __syncthreads();

    // E2E layer 1 row/col convs
    for (int q = tid; q < 8 * M_; q += 256) {
        int o = q & 7, h = q >> 3;
        float s = c1b[o];
#pragma unroll 2
        for (int wI = 0; wI < M_; ++wI) s = fmaf(A[h][wI], c1w[o * M_ + wI], s);
        a1[o][h] = s;
    }
    for (int q = tid; q < 8 * M_; q += 256) {
        int o = q & 7, wI = q >> 3;
        float s = c2b[o];
#pragma unroll 2
        for (int h = 0; h < M_; ++h) s = fmaf(A[h][wI], c2w[o * M_ + h], s);
        b1[o][wI] = s;
    }
    __syncthreads();

    // E2E layer 2 via on-the-fly o1 = leaky(a1+b1); float4 over output channel
    const float4* w3r4 = (const float4*)(ws + WS_W3R);
    const float4* w4r4 = (const float4*)(ws + WS_W4R);
    for (int q = tid; q < 720; q += 256) {
        if (q < 360) {
            int oq = q & 3, h = q >> 2;
            float4 acc = make_float4(c3b[4 * oq], c3b[4 * oq + 1],
                                     c3b[4 * oq + 2], c3b[4 * oq + 3]);
#pragma unroll
            for (int ci = 0; ci < 8; ++ci) {
                float av = a1[ci][h];
                for (int wI = 0; wI < M_; ++wI) {
                    float o1v = leaky(av + b1[ci][wI]);
                    float4 wv = w3r4[(ci * M_ + wI) * 4 + oq];
                    acc.x = fmaf(o1v, wv.x, acc.x);
                    acc.y = fmaf(o1v, wv.y, acc.y);
                    acc.z = fmaf(o1v, wv.z, acc.z);
                    acc.w = fmaf(o1v, wv.w, acc.w);
                }
            }
            a2s[4 * oq + 0][h] = acc.x;
            a2s[4 * oq + 1][h] = acc.y;
            a2s[4 * oq + 2][h] = acc.z;
            a2s[4 * oq + 3][h] = acc.w;
        } else {
            int q2 = q - 360;
            int oq = q2 & 3, wI = q2 >> 2;
            float4 acc = make_float4(c4b[4 * oq], c4b[4 * oq + 1],
                                     c4b[4 * oq + 2], c4b[4 * oq + 3]);
#pragma unroll
            for (int ci = 0; ci < 8; ++ci) {
                float bv = b1[ci][wI];
                for (int h = 0; h < M_; ++h) {
                    float o1v = leaky(a1[ci][h] + bv);
                    float4 wv = w4r4[(ci * M_ + h) * 4 + oq];
                    acc.x = fmaf(o1v, wv.x, acc.x);
                    acc.y = fmaf(o1v, wv.y, acc.y);
                    acc.z = fmaf(o1v, wv.z, acc.z);
                    acc.w = fmaf(o1v, wv.w, acc.w);
                }
            }
            b2s[4 * oq + 0][wI] = acc.x;
            b2s[4 * oq + 1][wI] = acc.y;
            b2s[4 * oq + 2][wI] = acc.z;
            b2s[4 * oq + 3][wI] = acc.w;
        }
    }
    __syncthreads();

    // e2n
    if (tid < M_) {
        float s = e2nb[0];
#pragma unroll
        for (int ci = 0; ci < 16; ++ci) {
            float av = a2s[ci][tid];
            for (int wI = 0; wI < M_; ++wI)
                s = fmaf(leaky(av + b2s[ci][wI]), e2nw[ci * M_ + wI], s);
        }
        e2n[tid] = leaky(s);
    }
    __syncthreads();
    // n2g
    if (tid < 64) {
        float s = n2gb[tid];
        for (int h = 0; h < M_; ++h) s = fmaf(e2n[h], n2gw[tid * M_ + h], s);
        n2g[tid] = leaky(s);
    }
    __syncthreads();
    if (tid < 128) {
        float s = d1b[tid];
        for (int k = 0; k < 64; ++k) s = fmaf(n2g[k], d1w[tid * 64 + k], s);
        h1[tid] = leaky(s);
    }
    __syncthreads();
    if (tid < 10) {
        float s = d2b[tid];
        for (int k = 0; k < 128; ++k) s = fmaf(h1[k], d2w[tid * 128 + k], s);
        h2[tid] = leaky(s);
    }
    __syncthreads();
    if (tid < 2) {
        float s = d3b[tid];
        for (int k = 0; k < 10; ++k) s = fmaf(h2[k], d3w[tid * 10 + k], s);
        out[CLS_OFF + b * 2 + tid] = leaky(s);
    }
}

// ---------------------------------------------------------------------------
extern "C" void kernel_launch(void* const* d_in, const int* in_sizes, int n_in,
                              void* d_out, int out_size, void* d_ws, size_t ws_size,
                              hipStream_t stream) {
    const float* x0 = (const float*)d_in[0];
    const float* rawx = (const float*)d_in[1];
    const float* c1w = (const float*)d_in[2];
    const float* c1b = (const float*)d_in[3];
    const float* c2w = (const float*)d_in[4];
    const float* c2b = (const float*)d_in[5];
    const float* c3w = (const float*)d_in[6];
    const float* c3b = (const float*)d_in[7];
    const float* c4w = (const float*)d_in[8];
    const float* c4b = (const float*)d_in[9];
    const float* e2nw = (const float*)d_in[10];
    const float* e2nb = (const float*)d_in[11];
    const float* n2gw = (const float*)d_in[12];
    const float* n2gb = (const float*)d_in[13];
    const float* d1w = (const float*)d_in[14];
    const float* d1b = (const float*)d_in[15];
    const float* d2w = (const float*)d_in[16];
    const float* d2b = (const float*)d_in[17];
    const float* d3w = (const float*)d_in[18];
    const float* d3b = (const float*)d_in[19];

    float* out = (float*)d_out;
    float* ws = (float*)d_ws;

    hipLaunchKernelGGL(k_norm, dim3(B_), dim3(256), 0, stream, x0, out);
    hipLaunchKernelGGL(k_gc, dim3(B_), dim3(256), 0, stream, out, rawx, ws);
    hipLaunchKernelGGL(k_prepack, dim3(2), dim3(256), 0, stream, c3w, c4w, ws);
    hipLaunchKernelGGL(k_power, dim3(B_), dim3(128), 0, stream, ws);
    hipLaunchKernelGGL(k_fista, dim3(MP / JB, B_), dim3(64), 0, stream, ws, out);
    hipLaunchKernelGGL(k_cnn, dim3(B_), dim3(256), 0, stream, out, ws,
                       c1w, c1b, c2w, c2b, c3b, c4b, e2nw, e2nb,
                       n2gw, n2gb, d1w, d1b, d2w, d2b, d3w, d3b, out);
}

// Round 2
// 1033.744 us; speedup vs baseline: 3.3031x; 3.3031x over previous
//
#include <hip/hip_runtime.h>
#include <math.h>

// ---------------------------------------------------------------------------
// Denoiser: normalize -> batched masked NNLS (FISTA, 500 it) -> BrainNetCNN
// R2: k_fista rewritten on MFMA (bf16x2 split, 3-product) -- fp32 update math.
//     k_gc split 4x; k_cnn e2n stage parallelized.
// ---------------------------------------------------------------------------

#define B_ 64
#define M_ 90
#define T_ 187
#define MP 96
#define NNLS_ITERS 500
#define POWER_ITERS 50
#define NEG_SLOPE 0.33f

#define MT_ (M_ * T_)                 // 16830
#define X0_OFF 0
#define A_OFF (B_ * MT_)              // 1077120
#define CLS_OFF (A_OFF + B_ * M_ * M_)// 1595520

// workspace layout (float offsets)
#define WS_G 0
#define WS_C (B_ * MP * MP)           // 589824
#define WS_STEP (2 * B_ * MP * MP)    // 1179648
#define WS_W3R (WS_STEP + B_)
#define WS_W4R (WS_W3R + 16 * 8 * M_)

typedef float f32x4 __attribute__((ext_vector_type(4)));
typedef short s16x8 __attribute__((ext_vector_type(8)));

__device__ __forceinline__ float leaky(float x) {
    return x >= 0.f ? x : NEG_SLOPE * x;
}

// ---------------------------------------------------------------------------
// Kernel 1: per-batch mean / absmax -> x0_pred
// ---------------------------------------------------------------------------
__global__ __launch_bounds__(256) void k_norm(const float* __restrict__ x0,
                                              float* __restrict__ out) {
    int b = blockIdx.x, tid = threadIdx.x;
    const float* x = x0 + b * MT_;
    float s = 0.f, mx = 0.f;
    for (int i = tid; i < MT_; i += 256) {
        float v = x[i];
        s += v;
        mx = fmaxf(mx, fabsf(v));
    }
    __shared__ float rs[256], rm[256];
    rs[tid] = s; rm[tid] = mx;
    __syncthreads();
    for (int st = 128; st > 0; st >>= 1) {
        if (tid < st) {
            rs[tid] += rs[tid + st];
            rm[tid] = fmaxf(rm[tid], rm[tid + st]);
        }
        __syncthreads();
    }
    float mean = rs[0] / (float)MT_;
    float mv = rm[0];
    float* o = out + X0_OFF + b * MT_;
    for (int i = tid; i < MT_; i += 256) {
        o[i] = (x[i] - mean) / mv;
    }
}

// ---------------------------------------------------------------------------
// Kernel 2: G[b][m][n], C[b][j][m]. grid (64 batches, 4 quarter-slabs)
// ---------------------------------------------------------------------------
__global__ __launch_bounds__(256) void k_gc(const float* __restrict__ out_x0,
                                            const float* __restrict__ rawx,
                                            float* __restrict__ ws) {
    int b = blockIdx.x, q = blockIdx.y, tid = threadIdx.x;
    const float* P = out_x0 + X0_OFF + b * MT_;
    const float* R = rawx + b * MT_;
    float* G = ws + WS_G + b * MP * MP;
    float* C = ws + WS_C + b * MP * MP;
    int lo = q * (MP * MP / 4), hi = lo + MP * MP / 4;
    for (int idx = lo + tid; idx < hi; idx += 256) {
        int n = idx % MP;
        int m = idx / MP;
        float g = 0.f, c = 0.f;
        if (n < M_ && m < M_) {
            const float* pm = P + m * T_;
            const float* pn = P + n * T_;
            const float* rn = R + n * T_;
#pragma unroll 4
            for (int t = 0; t < T_; ++t) {
                float v = pm[t];
                g = fmaf(pn[t], v, g);
                c = fmaf(rn[t], v, c);
            }
        }
        G[m * MP + n] = g;
        C[n * MP + m] = c;
    }
}

// ---------------------------------------------------------------------------
// Kernel 3: repack cnn3_w/cnn4_w -> [(c*90+hw)*16 + o]
// ---------------------------------------------------------------------------
__global__ __launch_bounds__(256) void k_prepack(const float* __restrict__ w3,
                                                 const float* __restrict__ w4,
                                                 float* __restrict__ ws) {
    int tid = threadIdx.x + blockIdx.x * 256;
    for (int i = tid; i < 16 * 8 * M_; i += 512) {
        int o = i & 15;
        int cw = i >> 4;
        int c = cw / M_;
        int w = cw % M_;
        ws[WS_W3R + i] = w3[(o * 8 + c) * M_ + w];
        ws[WS_W4R + i] = w4[(o * 8 + c) * M_ + w];
    }
}

// ---------------------------------------------------------------------------
// Kernel 4: power iteration -> step[b]
// ---------------------------------------------------------------------------
__global__ __launch_bounds__(128) void k_power(float* __restrict__ ws) {
    int b = blockIdx.x, tid = threadIdx.x;
    const float* G = ws + WS_G + b * MP * MP;
    __shared__ float Gp[M_][91];
    __shared__ float v[M_];
    __shared__ float red[128];
    for (int i = tid; i < M_ * M_; i += 128) {
        int r = i / M_, c = i % M_;
        Gp[r][c] = G[r * MP + c];
    }
    if (tid < M_) v[tid] = 1.f;
    __syncthreads();
    for (int it = 0; it < POWER_ITERS; ++it) {
        float s = 0.f;
        if (tid < M_) {
#pragma unroll 4
            for (int n = 0; n < M_; ++n) s = fmaf(Gp[tid][n], v[n], s);
        }
        red[tid] = (tid < M_) ? s * s : 0.f;
        __syncthreads();
        for (int st = 64; st > 0; st >>= 1) {
            if (tid < st) red[tid] += red[tid + st];
            __syncthreads();
        }
        float nrm = sqrtf(red[0]);
        if (tid < M_) v[tid] = s / (nrm + 1e-12f);
        __syncthreads();
    }
    float s = 0.f;
    if (tid < M_) {
#pragma unroll 4
        for (int n = 0; n < M_; ++n) s = fmaf(Gp[tid][n], v[n], s);
        s *= v[tid];
    }
    red[tid] = (tid < M_) ? s : 0.f;
    __syncthreads();
    for (int st = 64; st > 0; st >>= 1) {
        if (tid < st) red[tid] += red[tid + st];
        __syncthreads();
    }
    if (tid == 0) {
        float L = red[0] * 1.01f + 1e-8f;
        ws[WS_STEP + b] = 1.f / L;
    }
}

// ---------------------------------------------------------------------------
// Kernel 5: FISTA on MFMA. One wave per block; block = (j-tile of 16, batch).
// ACC[m][j] = sum_n G[m][n] Y[j][n]  (G symmetric == grad[j][m] transposed).
// bf16x2: grad ~= Ghi*Yhi + Ghi*Ylo + Glo*Yhi, fp32 accumulate, fp32 update.
// Ghi A-frags in VGPRs; Glo bf16 in LDS; Y (hi/lo bf16) bounced through LDS
// transposed buffer each iteration. Single wave -> no barriers.
// ---------------------------------------------------------------------------
#define YSTR 104   // bf16 row stride (208 B): (13j+..)&7 permutes bank groups

__global__ __launch_bounds__(64) void k_fista(const float* __restrict__ ws,
                                              float* __restrict__ out) {
    int b = blockIdx.y;
    int j0 = blockIdx.x * 16;
    int tid = threadIdx.x;
    int jl = tid & 15;   // lane row/col index
    int g = tid >> 4;    // 0..3 k-group

    const float* Gg = ws + WS_G + b * MP * MP;
    const float* Cg = ws + WS_C + b * MP * MP;
    float step = ws[WS_STEP + b];

    __shared__ unsigned short GloL[MP * YSTR];     // 19968 B
    __shared__ unsigned short Yt[2][16 * YSTR];    // 6656 B (hi, lo)

    // ---- fill Glo (bf16 residual of G) ----
    for (int i = tid; i < MP * (MP / 4); i += 64) {
        int row = i / (MP / 4);
        int n0 = (i % (MP / 4)) * 4;
        const float* src = Gg + row * MP + n0;
        unsigned int b0 = __float_as_uint(src[0]);
        unsigned int b1 = __float_as_uint(src[1]);
        unsigned int b2 = __float_as_uint(src[2]);
        unsigned int b3 = __float_as_uint(src[3]);
        float l0 = src[0] - __uint_as_float(b0 & 0xFFFF0000u);
        float l1 = src[1] - __uint_as_float(b1 & 0xFFFF0000u);
        float l2 = src[2] - __uint_as_float(b2 & 0xFFFF0000u);
        float l3 = src[3] - __uint_as_float(b3 & 0xFFFF0000u);
        unsigned int w0 = (__float_as_uint(l0) >> 16) | (__float_as_uint(l1) & 0xFFFF0000u);
        unsigned int w1 = (__float_as_uint(l2) >> 16) | (__float_as_uint(l3) & 0xFFFF0000u);
        *(uint2*)&GloL[row * YSTR + n0] = make_uint2(w0, w1);
    }
    // ---- zero Yt ----
    for (int i = tid; i < 2 * 16 * YSTR / 2; i += 64) {
        ((unsigned int*)Yt)[i] = 0u;
    }

    // ---- preload Ghi A-frags: ghi[mt][nc], lane holds A[row=jl][k=g*8+e] ----
    s16x8 ghi[6][3];
#pragma unroll
    for (int mt = 0; mt < 6; ++mt) {
#pragma unroll
        for (int nc = 0; nc < 3; ++nc) {
            const float* src = Gg + (mt * 16 + jl) * MP + nc * 32 + g * 8;
            s16x8 h;
#pragma unroll
            for (int e = 0; e < 8; ++e)
                h[e] = (short)(__float_as_uint(src[e]) >> 16);
            ghi[mt][nc] = h;
        }
    }

    // ---- load C in D-layout; init w/y ----
    float c[6][4], w[6][4], y[6][4];
#pragma unroll
    for (int mt = 0; mt < 6; ++mt) {
        const float* src = Cg + (j0 + jl) * MP + mt * 16 + g * 4;
#pragma unroll
        for (int r = 0; r < 4; ++r) {
            c[mt][r] = src[r];
            w[mt][r] = 0.f;
            y[mt][r] = 0.f;
        }
    }

    __syncthreads();   // single wave: cheap; orders LDS init (also other-lane fills)

    float t = 1.f;
    const unsigned short* yh_base = &Yt[0][jl * YSTR + g * 8];
    const unsigned short* yl_base = &Yt[1][jl * YSTR + g * 8];
    unsigned short* wr_hi = &Yt[0][jl * YSTR + g * 4];
    unsigned short* wr_lo = &Yt[1][jl * YSTR + g * 4];

    for (int it = 0; it < NNLS_ITERS; ++it) {
        // B-frags of current Y (hi and lo)
        s16x8 yh[3], yl[3];
#pragma unroll
        for (int nc = 0; nc < 3; ++nc) {
            yh[nc] = *(const s16x8*)(yh_base + nc * 32);
            yl[nc] = *(const s16x8*)(yl_base + nc * 32);
        }

        float t1 = 0.5f * (1.f + sqrtf(1.f + 4.f * t * t));
        float coef = (t - 1.f) / t1;
        t = t1;

#pragma unroll
        for (int mt = 0; mt < 6; ++mt) {
            f32x4 acc = {0.f, 0.f, 0.f, 0.f};
#pragma unroll
            for (int nc = 0; nc < 3; ++nc) {
                s16x8 glo = *(const s16x8*)(&GloL[(mt * 16 + jl) * YSTR + nc * 32 + g * 8]);
                acc = __builtin_amdgcn_mfma_f32_16x16x32_bf16(ghi[mt][nc], yh[nc], acc, 0, 0, 0);
                acc = __builtin_amdgcn_mfma_f32_16x16x32_bf16(ghi[mt][nc], yl[nc], acc, 0, 0, 0);
                acc = __builtin_amdgcn_mfma_f32_16x16x32_bf16(glo,          yh[nc], acc, 0, 0, 0);
            }
            // update 4 elements: (j = j0+jl, m = mt*16 + g*4 + r)
            unsigned int hb[4], lb[4];
#pragma unroll
            for (int r = 0; r < 4; ++r) {
                int mg = mt * 16 + g * 4 + r;
                float gr = acc[r] - c[mt][r];
                if (j0 + jl == mg) gr = 0.f;
                float w1v = fmaxf(fmaf(-step, gr, y[mt][r]), 0.f);
                float ynew = fmaf(coef, w1v - w[mt][r], w1v);
                w[mt][r] = w1v;
                y[mt][r] = ynew;
                unsigned int bits = __float_as_uint(ynew);
                hb[r] = bits & 0xFFFF0000u;
                float lo = ynew - __uint_as_float(hb[r]);
                lb[r] = __float_as_uint(lo);
            }
            unsigned int h0 = (hb[0] >> 16) | hb[1];
            unsigned int h1 = (hb[2] >> 16) | hb[3];
            unsigned int l0 = (lb[0] >> 16) | (lb[1] & 0xFFFF0000u);
            unsigned int l1 = (lb[2] >> 16) | (lb[3] & 0xFFFF0000u);
            *(uint2*)(wr_hi + mt * 16) = make_uint2(h0, h1);
            *(uint2*)(wr_lo + mt * 16) = make_uint2(l0, l1);
        }
        // single wave: DS ops retire in order; compiler inserts lgkmcnt waits
    }

    // ---- store w -> A[b][j][m] ----
#pragma unroll
    for (int mt = 0; mt < 6; ++mt) {
#pragma unroll
        for (int r = 0; r < 4; ++r) {
            int jg = j0 + jl;
            int mg = mt * 16 + g * 4 + r;
            if (jg < M_ && mg < M_)
                out[A_OFF + b * M_ * M_ + jg * M_ + mg] = w[mt][r];
        }
    }
}

// ---------------------------------------------------------------------------
// Kernel 6: BrainNetCNN head, one block per batch. e2n parallelized (R2).
// ---------------------------------------------------------------------------
__global__ __launch_bounds__(256) void k_cnn(
    const float* __restrict__ out_in, const float* __restrict__ ws,
    const float* __restrict__ c1w, const float* __restrict__ c1b,
    const float* __restrict__ c2w, const float* __restrict__ c2b,
    const float* __restrict__ c3b, const float* __restrict__ c4b,
    const float* __restrict__ e2nw, const float* __restrict__ e2nb,
    const float* __restrict__ n2gw, const float* __restrict__ n2gb,
    const float* __restrict__ d1w, const float* __restrict__ d1b,
    const float* __restrict__ d2w, const float* __restrict__ d2b,
    const float* __restrict__ d3w, const float* __restrict__ d3b,
    float* __restrict__ out) {
    int b = blockIdx.x, tid = threadIdx.x;
    __shared__ float A[M_][92];
    __shared__ float a1[8][92], b1[8][92];
    __shared__ float a2s[16][92], b2s[16][92];
    __shared__ float part[16][92];
    __shared__ float e2n[92], n2g[64], h1[128], h2[12];

    const float* Ag = out_in + A_OFF + b * M_ * M_;
    for (int i = tid; i < M_ * M_; i += 256) A[i / M_][i % M_] = Ag[i];
    __syncthreads();

    for (int q = tid; q < 8 * M_; q += 256) {
        int o = q & 7, h = q >> 3;
        float s = c1b[o];
#pragma unroll 2
        for (int wI = 0; wI < M_; ++wI) s = fmaf(A[h][wI], c1w[o * M_ + wI], s);
        a1[o][h] = s;
    }
    for (int q = tid; q < 8 * M_; q += 256) {
        int o = q & 7, wI = q >> 3;
        float s = c2b[o];
#pragma unroll 2
        for (int h = 0; h < M_; ++h) s = fmaf(A[h][wI], c2w[o * M_ + h], s);
        b1[o][wI] = s;
    }
    __syncthreads();

    const float4* w3r4 = (const float4*)(ws + WS_W3R);
    const float4* w4r4 = (const float4*)(ws + WS_W4R);
    for (int q = tid; q < 720; q += 256) {
        if (q < 360) {
            int oq = q & 3, h = q >> 2;
            float4 acc = make_float4(c3b[4 * oq], c3b[4 * oq + 1],
                                     c3b[4 * oq + 2], c3b[4 * oq + 3]);
#pragma unroll
            for (int ci = 0; ci < 8; ++ci) {
                float av = a1[ci][h];
                for (int wI = 0; wI < M_; ++wI) {
                    float o1v = leaky(av + b1[ci][wI]);
                    float4 wv = w3r4[(ci * M_ + wI) * 4 + oq];
                    acc.x = fmaf(o1v, wv.x, acc.x);
                    acc.y = fmaf(o1v, wv.y, acc.y);
                    acc.z = fmaf(o1v, wv.z, acc.z);
                    acc.w = fmaf(o1v, wv.w, acc.w);
                }
            }
            a2s[4 * oq + 0][h] = acc.x;
            a2s[4 * oq + 1][h] = acc.y;
            a2s[4 * oq + 2][h] = acc.z;
            a2s[4 * oq + 3][h] = acc.w;
        } else {
            int q2 = q - 360;
            int oq = q2 & 3, wI = q2 >> 2;
            float4 acc = make_float4(c4b[4 * oq], c4b[4 * oq + 1],
                                     c4b[4 * oq + 2], c4b[4 * oq + 3]);
#pragma unroll
            for (int ci = 0; ci < 8; ++ci) {
                float bv = b1[ci][wI];
                for (int h = 0; h < M_; ++h) {
                    float o1v = leaky(a1[ci][h] + bv);
                    float4 wv = w4r4[(ci * M_ + h) * 4 + oq];
                    acc.x = fmaf(o1v, wv.x, acc.x);
                    acc.y = fmaf(o1v, wv.y, acc.y);
                    acc.z = fmaf(o1v, wv.z, acc.z);
                    acc.w = fmaf(o1v, wv.w, acc.w);
                }
            }
            b2s[4 * oq + 0][wI] = acc.x;
            b2s[4 * oq + 1][wI] = acc.y;
            b2s[4 * oq + 2][wI] = acc.z;
            b2s[4 * oq + 3][wI] = acc.w;
        }
    }
    __syncthreads();

    // e2n: parallel over (h, ci) then reduce over ci
    for (int q = tid; q < 16 * M_; q += 256) {
        int ci = q & 15, h = q >> 4;
        float av = a2s[ci][h];
        float s = 0.f;
        for (int wI = 0; wI < M_; ++wI)
            s = fmaf(leaky(av + b2s[ci][wI]), e2nw[ci * M_ + wI], s);
        part[ci][h] = s;
    }
    __syncthreads();
    if (tid < M_) {
        float s = e2nb[0];
#pragma unroll
        for (int ci = 0; ci < 16; ++ci) s += part[ci][tid];
        e2n[tid] = leaky(s);
    }
    __syncthreads();
    if (tid < 64) {
        float s = n2gb[tid];
        for (int h = 0; h < M_; ++h) s = fmaf(e2n[h], n2gw[tid * M_ + h], s);
        n2g[tid] = leaky(s);
    }
    __syncthreads();
    if (tid < 128) {
        float s = d1b[tid];
        for (int k = 0; k < 64; ++k) s = fmaf(n2g[k], d1w[tid * 64 + k], s);
        h1[tid] = leaky(s);
    }
    __syncthreads();
    if (tid < 10) {
        float s = d2b[tid];
        for (int k = 0; k < 128; ++k) s = fmaf(h1[k], d2w[tid * 128 + k], s);
        h2[tid] = leaky(s);
    }
    __syncthreads();
    if (tid < 2) {
        float s = d3b[tid];
        for (int k = 0; k < 10; ++k) s = fmaf(h2[k], d3w[tid * 10 + k], s);
        out[CLS_OFF + b * 2 + tid] = leaky(s);
    }
}

// ---------------------------------------------------------------------------
extern "C" void kernel_launch(void* const* d_in, const int* in_sizes, int n_in,
                              void* d_out, int out_size, void* d_ws, size_t ws_size,
                              hipStream_t stream) {
    const float* x0 = (const float*)d_in[0];
    const float* rawx = (const float*)d_in[1];
    const float* c1w = (const float*)d_in[2];
    const float* c1b = (const float*)d_in[3];
    const float* c2w = (const float*)d_in[4];
    const float* c2b = (const float*)d_in[5];
    const float* c3w = (const float*)d_in[6];
    const float* c3b = (const float*)d_in[7];
    const float* c4w = (const float*)d_in[8];
    const float* c4b = (const float*)d_in[9];
    const float* e2nw = (const float*)d_in[10];
    const float* e2nb = (const float*)d_in[11];
    const float* n2gw = (const float*)d_in[12];
    const float* n2gb = (const float*)d_in[13];
    const float* d1w = (const float*)d_in[14];
    const float* d1b = (const float*)d_in[15];
    const float* d2w = (const float*)d_in[16];
    const float* d2b = (const float*)d_in[17];
    const float* d3w = (const float*)d_in[18];
    const float* d3b = (const float*)d_in[19];

    float* out = (float*)d_out;
    float* ws = (float*)d_ws;

    hipLaunchKernelGGL(k_norm, dim3(B_), dim3(256), 0, stream, x0, out);
    hipLaunchKernelGGL(k_gc, dim3(B_, 4), dim3(256), 0, stream, out, rawx, ws);
    hipLaunchKernelGGL(k_prepack, dim3(2), dim3(256), 0, stream, c3w, c4w, ws);
    hipLaunchKernelGGL(k_power, dim3(B_), dim3(128), 0, stream, ws);
    hipLaunchKernelGGL(k_fista, dim3(MP / 16, B_), dim3(64), 0, stream, ws, out);
    hipLaunchKernelGGL(k_cnn, dim3(B_), dim3(256), 0, stream, out, ws,
                       c1w, c1b, c2w, c2b, c3b, c4b, e2nw, e2nb,
                       n2gw, n2gb, d1w, d1b, d2w, d2b, d3w, d3b, out);
}

// Round 4
// 724.690 us; speedup vs baseline: 4.7118x; 1.4265x over previous
//
#include <hip/hip_runtime.h>
#include <math.h>

// ---------------------------------------------------------------------------
// Denoiser: normalize -> batched masked NNLS (FISTA, 500 it) -> BrainNetCNN
// R3 (resubmit; R3 round lost to GPU capacity): k_fista 3-wave m-split
// (G hi+lo fully in VGPRs, Y ping-pong in LDS, 1 barrier/iter);
// k_gc LDS-tiled 6x3 register tiles; k_power 1-wave.
// ---------------------------------------------------------------------------

#define B_ 64
#define M_ 90
#define T_ 187
#define MP 96
#define NNLS_ITERS 500
#define POWER_ITERS 50
#define NEG_SLOPE 0.33f

#define MT_ (M_ * T_)                 // 16830
#define X0_OFF 0
#define A_OFF (B_ * MT_)              // 1077120
#define CLS_OFF (A_OFF + B_ * M_ * M_)// 1595520

// workspace layout (float offsets)
#define WS_G 0
#define WS_C (B_ * MP * MP)           // 589824
#define WS_STEP (2 * B_ * MP * MP)    // 1179648
#define WS_W3R (WS_STEP + B_)
#define WS_W4R (WS_W3R + 16 * 8 * M_)

typedef float f32x4 __attribute__((ext_vector_type(4)));
typedef short s16x8 __attribute__((ext_vector_type(8)));

__device__ __forceinline__ float leaky(float x) {
    return x >= 0.f ? x : NEG_SLOPE * x;
}

// ---------------------------------------------------------------------------
// Kernel 1: per-batch mean / absmax -> x0_pred
// ---------------------------------------------------------------------------
__global__ __launch_bounds__(256) void k_norm(const float* __restrict__ x0,
                                              float* __restrict__ out) {
    int b = blockIdx.x, tid = threadIdx.x;
    const float* x = x0 + b * MT_;
    float s = 0.f, mx = 0.f;
    for (int i = tid; i < MT_; i += 256) {
        float v = x[i];
        s += v;
        mx = fmaxf(mx, fabsf(v));
    }
    __shared__ float rs[256], rm[256];
    rs[tid] = s; rm[tid] = mx;
    __syncthreads();
    for (int st = 128; st > 0; st >>= 1) {
        if (tid < st) {
            rs[tid] += rs[tid + st];
            rm[tid] = fmaxf(rm[tid], rm[tid + st]);
        }
        __syncthreads();
    }
    float mean = rs[0] / (float)MT_;
    float mv = rm[0];
    float* o = out + X0_OFF + b * MT_;
    for (int i = tid; i < MT_; i += 256) {
        o[i] = (x[i] - mean) / mv;
    }
}

// ---------------------------------------------------------------------------
// Kernel 2 (R3): LDS-tiled Gram. grid (batch, n-half). P (96 rows) + R (48
// rows) staged at stride 193 (conflict-free column reads). Thread = 6m x 3n
// register tile: 12 LDS b32 + 36 fma per t-step.
// ---------------------------------------------------------------------------
#define TSTR 193
__global__ __launch_bounds__(256) void k_gc(const float* __restrict__ out_x0,
                                            const float* __restrict__ rawx,
                                            float* __restrict__ ws) {
    int b = blockIdx.x, nh = blockIdx.y, tid = threadIdx.x;
    __shared__ float Ps[MP * TSTR];      // 74112 B
    __shared__ float Rs[48 * TSTR];      // 37056 B

    for (int i = tid; i < MP * TSTR; i += 256) Ps[i] = 0.f;
    for (int i = tid; i < 48 * TSTR; i += 256) Rs[i] = 0.f;
    __syncthreads();

    const float* P = out_x0 + X0_OFF + b * MT_;
    const float* R = rawx + b * MT_;
    for (int i = tid; i < MT_; i += 256) {
        int m = i / T_, t = i - m * T_;
        Ps[m * TSTR + t] = P[i];
    }
    for (int i = tid; i < 48 * T_; i += 256) {
        int k = i / T_, t = i - k * T_;
        int r = nh * 48 + k;
        if (r < M_) Rs[k * TSTR + t] = R[r * T_ + t];
    }
    __syncthreads();

    int tn = tid & 15;        // n-tile within half: 3 cols
    int tm = tid >> 4;        // m-tile: 6 rows
    const float* pmp = &Ps[(tm * 6) * TSTR];
    const float* pnp = &Ps[(nh * 48 + tn * 3) * TSTR];
    const float* rnp = &Rs[(tn * 3) * TSTR];

    float accG[6][3], accC[6][3];
#pragma unroll
    for (int i = 0; i < 6; ++i)
#pragma unroll
        for (int k = 0; k < 3; ++k) { accG[i][k] = 0.f; accC[i][k] = 0.f; }

#pragma unroll 2
    for (int t = 0; t < T_; ++t) {
        float pm[6], pn[3], rn[3];
#pragma unroll
        for (int i = 0; i < 6; ++i) pm[i] = pmp[i * TSTR + t];
#pragma unroll
        for (int k = 0; k < 3; ++k) { pn[k] = pnp[k * TSTR + t]; rn[k] = rnp[k * TSTR + t]; }
#pragma unroll
        for (int i = 0; i < 6; ++i)
#pragma unroll
            for (int k = 0; k < 3; ++k) {
                accG[i][k] = fmaf(pm[i], pn[k], accG[i][k]);
                accC[i][k] = fmaf(pm[i], rn[k], accC[i][k]);
            }
    }

    float* G = ws + WS_G + b * MP * MP;
    float* C = ws + WS_C + b * MP * MP;
#pragma unroll
    for (int i = 0; i < 6; ++i)
#pragma unroll
        for (int k = 0; k < 3; ++k) {
            int m = tm * 6 + i;
            int n = nh * 48 + tn * 3 + k;
            G[m * MP + n] = accG[i][k];
            C[n * MP + m] = accC[i][k];
        }
}

// ---------------------------------------------------------------------------
// Kernel 3: repack cnn3_w/cnn4_w -> [(c*90+hw)*16 + o]
// ---------------------------------------------------------------------------
__global__ __launch_bounds__(256) void k_prepack(const float* __restrict__ w3,
                                                 const float* __restrict__ w4,
                                                 float* __restrict__ ws) {
    int tid = threadIdx.x + blockIdx.x * 256;
    for (int i = tid; i < 16 * 8 * M_; i += 512) {
        int o = i & 15;
        int cw = i >> 4;
        int c = cw / M_;
        int w = cw % M_;
        ws[WS_W3R + i] = w3[(o * 8 + c) * M_ + w];
        ws[WS_W4R + i] = w4[(o * 8 + c) * M_ + w];
    }
}

// ---------------------------------------------------------------------------
// Kernel 4 (R3): power iteration, one wave per batch, no barriers.
// G staged at dword-stride 100 (b128 row reads conflict-free), v broadcast.
// ---------------------------------------------------------------------------
#define GSTR 100
__global__ __launch_bounds__(64) void k_power(float* __restrict__ ws) {
    int b = blockIdx.x, lane = threadIdx.x;
    const float* Gg = ws + WS_G + b * MP * MP;
    __shared__ float Gs[MP * GSTR];   // 38400 B
    __shared__ float vs[MP];

    for (int i = lane; i < MP * MP; i += 64) {
        int m = i / MP, n = i - m * MP;
        Gs[m * GSTR + n] = Gg[i];
    }
    vs[lane] = (lane < M_) ? 1.f : 0.f;
    if (lane < 32) vs[64 + lane] = (64 + lane < M_) ? 1.f : 0.f;
    // single wave: DS ops retire in order; no barrier needed

    const float4* g0 = (const float4*)&Gs[lane * GSTR];
    const float4* g1 = (const float4*)&Gs[(64 + (lane & 31)) * GSTR];
    const float4* v4 = (const float4*)vs;

    float r0 = 0.f, r1 = 0.f;
    for (int it = 0; it <= POWER_ITERS; ++it) {
        r0 = 0.f; r1 = 0.f;
#pragma unroll 6
        for (int k = 0; k < MP / 4; ++k) {
            float4 gv = g0[k];
            float4 vv = v4[k];
            r0 = fmaf(gv.x, vv.x, r0);
            r0 = fmaf(gv.y, vv.y, r0);
            r0 = fmaf(gv.z, vv.z, r0);
            r0 = fmaf(gv.w, vv.w, r0);
        }
        if (lane < 32) {
#pragma unroll 6
            for (int k = 0; k < MP / 4; ++k) {
                float4 gv = g1[k];
                float4 vv = v4[k];
                r1 = fmaf(gv.x, vv.x, r1);
                r1 = fmaf(gv.y, vv.y, r1);
                r1 = fmaf(gv.z, vv.z, r1);
                r1 = fmaf(gv.w, vv.w, r1);
            }
        }
        if (it == POWER_ITERS) break;
        float s = r0 * r0 + ((lane < 32) ? r1 * r1 : 0.f);
#pragma unroll
        for (int d = 1; d < 64; d <<= 1) s += __shfl_xor(s, d, 64);
        float inv = 1.f / (sqrtf(s) + 1e-12f);
        vs[lane] = r0 * inv;
        if (lane < 32) vs[64 + lane] = r1 * inv;
    }
    // Rayleigh: L = sum v[m] * (G v)[m]
    float s = vs[lane] * r0 + ((lane < 32) ? vs[64 + lane] * r1 : 0.f);
#pragma unroll
    for (int d = 1; d < 64; d <<= 1) s += __shfl_xor(s, d, 64);
    if (lane == 0) ws[WS_STEP + b] = 1.f / (s * 1.01f + 1e-8f);
}

// ---------------------------------------------------------------------------
// Kernel 5 (R3): FISTA on MFMA, 3 waves per block (m-split: 2 m-tiles/wave).
// G hi+lo frags in VGPRs. Y (hi/lo bf16) ping-pong in LDS, [j][n] layout,
// 1 barrier per iteration. acc split in 2 chains to halve MFMA dep depth.
// ---------------------------------------------------------------------------
#define YSTR 104   // bf16 row stride: reads/writes uniform across banks

__global__ __launch_bounds__(192) void k_fista(const float* __restrict__ ws,
                                               float* __restrict__ out) {
    int b = blockIdx.y;
    int j0 = blockIdx.x * 16;
    int tid = threadIdx.x;
    int wid = tid >> 6;          // 0..2 : m-tiles {2w, 2w+1}
    int lane = tid & 63;
    int jl = lane & 15;          // j-local (MFMA col)
    int g = lane >> 4;           // 0..3 k-group

    const float* Gg = ws + WS_G + b * MP * MP;
    const float* Cg = ws + WS_C + b * MP * MP;
    float step = ws[WS_STEP + b];

    __shared__ unsigned short Yt[2][2][16 * YSTR];  // [buf][hi/lo][j][n] 13312 B

    for (int i = tid; i < 2 * 2 * 16 * YSTR / 2; i += 192)
        ((unsigned int*)Yt)[i] = 0u;

    // ---- G fragments (hi + lo) in registers: 2 m-tiles x 3 n-chunks ----
    s16x8 ghi[2][3], glo[2][3];
#pragma unroll
    for (int ml = 0; ml < 2; ++ml)
#pragma unroll
        for (int nc = 0; nc < 3; ++nc) {
            const float* src = Gg + ((wid * 2 + ml) * 16 + jl) * MP + nc * 32 + g * 8;
            s16x8 h, l;
#pragma unroll
            for (int e = 0; e < 8; ++e) {
                float f = src[e];
                unsigned int hb = __float_as_uint(f) & 0xFFFF0000u;
                h[e] = (short)(hb >> 16);
                float lo = f - __uint_as_float(hb);
                l[e] = (short)(__float_as_uint(lo) >> 16);
            }
            ghi[ml][nc] = h;
            glo[ml][nc] = l;
        }

    // ---- C in D-layout; init w/y ----
    float c[2][4], w[2][4], y[2][4];
#pragma unroll
    for (int ml = 0; ml < 2; ++ml) {
        const float* src = Cg + (j0 + jl) * MP + (wid * 2 + ml) * 16 + g * 4;
#pragma unroll
        for (int r = 0; r < 4; ++r) {
            c[ml][r] = src[r];
            w[ml][r] = 0.f;
            y[ml][r] = 0.f;
        }
    }

    // read/write LDS bases (per buf, per hi/lo)
    const unsigned short* rb[2][2];
    unsigned short* wb[2][2];
#pragma unroll
    for (int bu = 0; bu < 2; ++bu)
#pragma unroll
        for (int hl = 0; hl < 2; ++hl) {
            rb[bu][hl] = &Yt[bu][hl][jl * YSTR + g * 8];
            wb[bu][hl] = &Yt[bu][hl][jl * YSTR + wid * 32 + g * 4];
        }

    float t = 1.f;
    __syncthreads();

#define FISTA_BODY(CUR, NXT)                                                   \
    {                                                                          \
        s16x8 yh[3], yl[3];                                                    \
        _Pragma("unroll")                                                      \
        for (int nc = 0; nc < 3; ++nc) {                                       \
            yh[nc] = *(const s16x8*)(rb[CUR][0] + nc * 32);                    \
            yl[nc] = *(const s16x8*)(rb[CUR][1] + nc * 32);                    \
        }                                                                      \
        float t1 = 0.5f * (1.f + sqrtf(1.f + 4.f * t * t));                    \
        float coef = (t - 1.f) / t1;                                           \
        t = t1;                                                                \
        _Pragma("unroll")                                                      \
        for (int ml = 0; ml < 2; ++ml) {                                       \
            f32x4 a1 = {0.f, 0.f, 0.f, 0.f}, a2 = {0.f, 0.f, 0.f, 0.f};        \
            _Pragma("unroll")                                                  \
            for (int nc = 0; nc < 3; ++nc)                                     \
                a1 = __builtin_amdgcn_mfma_f32_16x16x32_bf16(ghi[ml][nc], yh[nc], a1, 0, 0, 0); \
            _Pragma("unroll")                                                  \
            for (int nc = 0; nc < 3; ++nc) {                                   \
                a2 = __builtin_amdgcn_mfma_f32_16x16x32_bf16(ghi[ml][nc], yl[nc], a2, 0, 0, 0); \
                a2 = __builtin_amdgcn_mfma_f32_16x16x32_bf16(glo[ml][nc], yh[nc], a2, 0, 0, 0); \
            }                                                                  \
            unsigned int hb[4], lb[4];                                         \
            _Pragma("unroll")                                                  \
            for (int r = 0; r < 4; ++r) {                                      \
                int mg = (wid * 2 + ml) * 16 + g * 4 + r;                      \
                float gr = (a1[r] + a2[r]) - c[ml][r];                         \
                if (j0 + jl == mg) gr = 0.f;                                   \
                float w1v = fmaxf(fmaf(-step, gr, y[ml][r]), 0.f);             \
                float yn = fmaf(coef, w1v - w[ml][r], w1v);                    \
                w[ml][r] = w1v;                                                \
                y[ml][r] = yn;                                                 \
                hb[r] = __float_as_uint(yn) & 0xFFFF0000u;                     \
                float lo = yn - __uint_as_float(hb[r]);                        \
                lb[r] = __float_as_uint(lo);                                   \
            }                                                                  \
            unsigned int h0 = (hb[0] >> 16) | hb[1];                           \
            unsigned int h1 = (hb[2] >> 16) | hb[3];                           \
            unsigned int l0 = (lb[0] >> 16) | (lb[1] & 0xFFFF0000u);           \
            unsigned int l1 = (lb[2] >> 16) | (lb[3] & 0xFFFF0000u);           \
            *(uint2*)(wb[NXT][0] + ml * 16) = make_uint2(h0, h1);              \
            *(uint2*)(wb[NXT][1] + ml * 16) = make_uint2(l0, l1);              \
        }                                                                      \
        __syncthreads();                                                       \
    }

    for (int it = 0; it < NNLS_ITERS / 2; ++it) {
        FISTA_BODY(0, 1)
        FISTA_BODY(1, 0)
    }
#undef FISTA_BODY

    // ---- store w -> A[b][j][m] ----
    int jg = j0 + jl;
#pragma unroll
    for (int ml = 0; ml < 2; ++ml)
#pragma unroll
        for (int r = 0; r < 4; ++r) {
            int mg = (wid * 2 + ml) * 16 + g * 4 + r;
            if (jg < M_ && mg < M_)
                out[A_OFF + b * M_ * M_ + jg * M_ + mg] = w[ml][r];
        }
}

// ---------------------------------------------------------------------------
// Kernel 6: BrainNetCNN head, one block per batch.
// ---------------------------------------------------------------------------
__global__ __launch_bounds__(256) void k_cnn(
    const float* __restrict__ out_in, const float* __restrict__ ws,
    const float* __restrict__ c1w, const float* __restrict__ c1b,
    const float* __restrict__ c2w, const float* __restrict__ c2b,
    const float* __restrict__ c3b, const float* __restrict__ c4b,
    const float* __restrict__ e2nw, const float* __restrict__ e2nb,
    const float* __restrict__ n2gw, const float* __restrict__ n2gb,
    const float* __restrict__ d1w, const float* __restrict__ d1b,
    const float* __restrict__ d2w, const float* __restrict__ d2b,
    const float* __restrict__ d3w, const float* __restrict__ d3b,
    float* __restrict__ out) {
    int b = blockIdx.x, tid = threadIdx.x;
    __shared__ float A[M_][92];
    __shared__ float a1[8][92], b1[8][92];
    __shared__ float a2s[16][92], b2s[16][92];
    __shared__ float part[16][92];
    __shared__ float e2n[92], n2g[64], h1[128], h2[12];

    const float* Ag = out_in + A_OFF + b * M_ * M_;
    for (int i = tid; i < M_ * M_; i += 256) A[i / M_][i % M_] = Ag[i];
    __syncthreads();

    for (int q = tid; q < 8 * M_; q += 256) {
        int o = q & 7, h = q >> 3;
        float s = c1b[o];
#pragma unroll 2
        for (int wI = 0; wI < M_; ++wI) s = fmaf(A[h][wI], c1w[o * M_ + wI], s);
        a1[o][h] = s;
    }
    for (int q = tid; q < 8 * M_; q += 256) {
        int o = q & 7, wI = q >> 3;
        float s = c2b[o];
#pragma unroll 2
        for (int h = 0; h < M_; ++h) s = fmaf(A[h][wI], c2w[o * M_ + h], s);
        b1[o][wI] = s;
    }
    __syncthreads();

    const float4* w3r4 = (const float4*)(ws + WS_W3R);
    const float4* w4r4 = (const float4*)(ws + WS_W4R);
    for (int q = tid; q < 720; q += 256) {
        if (q < 360) {
            int oq = q & 3, h = q >> 2;
            float4 acc = make_float4(c3b[4 * oq], c3b[4 * oq + 1],
                                     c3b[4 * oq + 2], c3b[4 * oq + 3]);
#pragma unroll
            for (int ci = 0; ci < 8; ++ci) {
                float av = a1[ci][h];
                for (int wI = 0; wI < M_; ++wI) {
                    float o1v = leaky(av + b1[ci][wI]);
                    float4 wv = w3r4[(ci * M_ + wI) * 4 + oq];
                    acc.x = fmaf(o1v, wv.x, acc.x);
                    acc.y = fmaf(o1v, wv.y, acc.y);
                    acc.z = fmaf(o1v, wv.z, acc.z);
                    acc.w = fmaf(o1v, wv.w, acc.w);
                }
            }
            a2s[4 * oq + 0][h] = acc.x;
            a2s[4 * oq + 1][h] = acc.y;
            a2s[4 * oq + 2][h] = acc.z;
            a2s[4 * oq + 3][h] = acc.w;
        } else {
            int q2 = q - 360;
            int oq = q2 & 3, wI = q2 >> 2;
            float4 acc = make_float4(c4b[4 * oq], c4b[4 * oq + 1],
                                     c4b[4 * oq + 2], c4b[4 * oq + 3]);
#pragma unroll
            for (int ci = 0; ci < 8; ++ci) {
                float bv = b1[ci][wI];
                for (int h = 0; h < M_; ++h) {
                    float o1v = leaky(a1[ci][h] + bv);
                    float4 wv = w4r4[(ci * M_ + h) * 4 + oq];
                    acc.x = fmaf(o1v, wv.x, acc.x);
                    acc.y = fmaf(o1v, wv.y, acc.y);
                    acc.z = fmaf(o1v, wv.z, acc.z);
                    acc.w = fmaf(o1v, wv.w, acc.w);
                }
            }
            b2s[4 * oq + 0][wI] = acc.x;
            b2s[4 * oq + 1][wI] = acc.y;
            b2s[4 * oq + 2][wI] = acc.z;
            b2s[4 * oq + 3][wI] = acc.w;
        }
    }
    __syncthreads();

    for (int q = tid; q < 16 * M_; q += 256) {
        int ci = q & 15, h = q >> 4;
        float av = a2s[ci][h];
        float s = 0.f;
        for (int wI = 0; wI < M_; ++wI)
            s = fmaf(leaky(av + b2s[ci][wI]), e2nw[ci * M_ + wI], s);
        part[ci][h] = s;
    }
    __syncthreads();
    if (tid < M_) {
        float s = e2nb[0];
#pragma unroll
        for (int ci = 0; ci < 16; ++ci) s += part[ci][tid];
        e2n[tid] = leaky(s);
    }
    __syncthreads();
    if (tid < 64) {
        float s = n2gb[tid];
        for (int h = 0; h < M_; ++h) s = fmaf(e2n[h], n2gw[tid * M_ + h], s);
        n2g[tid] = leaky(s);
    }
    __syncthreads();
    if (tid < 128) {
        float s = d1b[tid];
        for (int k = 0; k < 64; ++k) s = fmaf(n2g[k], d1w[tid * 64 + k], s);
        h1[tid] = leaky(s);
    }
    __syncthreads();
    if (tid < 10) {
        float s = d2b[tid];
        for (int k = 0; k < 128; ++k) s = fmaf(h1[k], d2w[tid * 128 + k], s);
        h2[tid] = leaky(s);
    }
    __syncthreads();
    if (tid < 2) {
        float s = d3b[tid];
        for (int k = 0; k < 10; ++k) s = fmaf(h2[k], d3w[tid * 10 + k], s);
        out[CLS_OFF + b * 2 + tid] = leaky(s);
    }
}

// ---------------------------------------------------------------------------
extern "C" void kernel_launch(void* const* d_in, const int* in_sizes, int n_in,
                              void* d_out, int out_size, void* d_ws, size_t ws_size,
                              hipStream_t stream) {
    const float* x0 = (const float*)d_in[0];
    const float* rawx = (const float*)d_in[1];
    const float* c1w = (const float*)d_in[2];
    const float* c1b = (const float*)d_in[3];
    const float* c2w = (const float*)d_in[4];
    const float* c2b = (const float*)d_in[5];
    const float* c3w = (const float*)d_in[6];
    const float* c3b = (const float*)d_in[7];
    const float* c4w = (const float*)d_in[8];
    const float* c4b = (const float*)d_in[9];
    const float* e2nw = (const float*)d_in[10];
    const float* e2nb = (const float*)d_in[11];
    const float* n2gw = (const float*)d_in[12];
    const float* n2gb = (const float*)d_in[13];
    const float* d1w = (const float*)d_in[14];
    const float* d1b = (const float*)d_in[15];
    const float* d2w = (const float*)d_in[16];
    const float* d2b = (const float*)d_in[17];
    const float* d3w = (const float*)d_in[18];
    const float* d3b = (const float*)d_in[19];

    float* out = (float*)d_out;
    float* ws = (float*)d_ws;

    hipLaunchKernelGGL(k_norm, dim3(B_), dim3(256), 0, stream, x0, out);
    hipLaunchKernelGGL(k_gc, dim3(B_, 2), dim3(256), 0, stream, out, rawx, ws);
    hipLaunchKernelGGL(k_prepack, dim3(2), dim3(256), 0, stream, c3w, c4w, ws);
    hipLaunchKernelGGL(k_power, dim3(B_), dim3(64), 0, stream, ws);
    hipLaunchKernelGGL(k_fista, dim3(MP / 16, B_), dim3(192), 0, stream, ws, out);
    hipLaunchKernelGGL(k_cnn, dim3(B_), dim3(256), 0, stream, out, ws,
                       c1w, c1b, c2w, c2b, c3b, c4b, e2nw, e2nb,
                       n2gw, n2gb, d1w, d1b, d2w, d2b, d3w, d3b, out);
}

// Round 6
// 713.673 us; speedup vs baseline: 4.7845x; 1.0154x over previous
//
#include <hip/hip_runtime.h>
#include <math.h>

// ---------------------------------------------------------------------------
// Denoiser: normalize -> batched masked NNLS (FISTA, 500 it) -> BrainNetCNN
// R5 (resubmit; R5 round lost to GPU capacity): k_fista 6-wave m-split
// (1 m-tile/wave, 9 MFMA in 3 chains, 2.25 waves/SIMD); k_norm folded into
// k_gc (normalize during LDS staging).
// ---------------------------------------------------------------------------

#define B_ 64
#define M_ 90
#define T_ 187
#define MP 96
#define NNLS_ITERS 500
#define POWER_ITERS 50
#define NEG_SLOPE 0.33f

#define MT_ (M_ * T_)                 // 16830
#define X0_OFF 0
#define A_OFF (B_ * MT_)              // 1077120
#define CLS_OFF (A_OFF + B_ * M_ * M_)// 1595520

// workspace layout (float offsets)
#define WS_G 0
#define WS_C (B_ * MP * MP)           // 589824
#define WS_STEP (2 * B_ * MP * MP)    // 1179648
#define WS_W3R (WS_STEP + B_)
#define WS_W4R (WS_W3R + 16 * 8 * M_)

typedef float f32x4 __attribute__((ext_vector_type(4)));
typedef short s16x8 __attribute__((ext_vector_type(8)));

__device__ __forceinline__ float leaky(float x) {
    return x >= 0.f ? x : NEG_SLOPE * x;
}

// ---------------------------------------------------------------------------
// Kernel 2 (R5): fused normalize + Gram. grid (batch, n-half).
// Per-block: block-reduce mean/absmax of x0[b] (bit-identical structure to
// old k_norm), stage normalized P (96 rows) + R (48 rows) at stride 193,
// 6m x 3n register tiles. nh==0 block writes x0_pred to d_out.
// ---------------------------------------------------------------------------
#define TSTR 193
__global__ __launch_bounds__(256) void k_gc(const float* __restrict__ x0,
                                            const float* __restrict__ rawx,
                                            float* __restrict__ ws,
                                            float* __restrict__ out) {
    int b = blockIdx.x, nh = blockIdx.y, tid = threadIdx.x;
    __shared__ float Ps[MP * TSTR];      // 74112 B
    __shared__ float Rs[48 * TSTR];      // 37056 B
    __shared__ float rs[256], rm[256];

    const float* x = x0 + b * MT_;
    // --- block reduce mean / absmax (same structure as old k_norm) ---
    {
        float s = 0.f, mx = 0.f;
        for (int i = tid; i < MT_; i += 256) {
            float v = x[i];
            s += v;
            mx = fmaxf(mx, fabsf(v));
        }
        rs[tid] = s; rm[tid] = mx;
    }
    __syncthreads();
    for (int st = 128; st > 0; st >>= 1) {
        if (tid < st) {
            rs[tid] += rs[tid + st];
            rm[tid] = fmaxf(rm[tid], rm[tid + st]);
        }
        __syncthreads();
    }
    float mean = rs[0] / (float)MT_;
    float mv = rm[0];

    // --- zero pad rows, stage normalized P and R, write x0_pred (nh==0) ---
    for (int i = tid; i < MP * TSTR; i += 256) Ps[i] = 0.f;
    for (int i = tid; i < 48 * TSTR; i += 256) Rs[i] = 0.f;
    __syncthreads();

    const float* R = rawx + b * MT_;
    float* o = out + X0_OFF + b * MT_;
    for (int i = tid; i < MT_; i += 256) {
        int m = i / T_, t = i - m * T_;
        float pv = (x[i] - mean) / mv;
        Ps[m * TSTR + t] = pv;
        if (nh == 0) o[i] = pv;
    }
    for (int i = tid; i < 48 * T_; i += 256) {
        int k = i / T_, t = i - k * T_;
        int r = nh * 48 + k;
        if (r < M_) Rs[k * TSTR + t] = R[r * T_ + t];
    }
    __syncthreads();

    int tn = tid & 15;        // n-tile within half: 3 cols
    int tm = tid >> 4;        // m-tile: 6 rows
    const float* pmp = &Ps[(tm * 6) * TSTR];
    const float* pnp = &Ps[(nh * 48 + tn * 3) * TSTR];
    const float* rnp = &Rs[(tn * 3) * TSTR];

    float accG[6][3], accC[6][3];
#pragma unroll
    for (int i = 0; i < 6; ++i)
#pragma unroll
        for (int k = 0; k < 3; ++k) { accG[i][k] = 0.f; accC[i][k] = 0.f; }

#pragma unroll 2
    for (int t = 0; t < T_; ++t) {
        float pm[6], pn[3], rn[3];
#pragma unroll
        for (int i = 0; i < 6; ++i) pm[i] = pmp[i * TSTR + t];
#pragma unroll
        for (int k = 0; k < 3; ++k) { pn[k] = pnp[k * TSTR + t]; rn[k] = rnp[k * TSTR + t]; }
#pragma unroll
        for (int i = 0; i < 6; ++i)
#pragma unroll
            for (int k = 0; k < 3; ++k) {
                accG[i][k] = fmaf(pm[i], pn[k], accG[i][k]);
                accC[i][k] = fmaf(pm[i], rn[k], accC[i][k]);
            }
    }

    float* G = ws + WS_G + b * MP * MP;
    float* C = ws + WS_C + b * MP * MP;
#pragma unroll
    for (int i = 0; i < 6; ++i)
#pragma unroll
        for (int k = 0; k < 3; ++k) {
            int m = tm * 6 + i;
            int n = nh * 48 + tn * 3 + k;
            G[m * MP + n] = accG[i][k];
            C[n * MP + m] = accC[i][k];
        }
}

// ---------------------------------------------------------------------------
// Kernel 3: repack cnn3_w/cnn4_w -> [(c*90+hw)*16 + o]
// ---------------------------------------------------------------------------
__global__ __launch_bounds__(256) void k_prepack(const float* __restrict__ w3,
                                                 const float* __restrict__ w4,
                                                 float* __restrict__ ws) {
    int tid = threadIdx.x + blockIdx.x * 256;
    for (int i = tid; i < 16 * 8 * M_; i += 512) {
        int o = i & 15;
        int cw = i >> 4;
        int c = cw / M_;
        int w = cw % M_;
        ws[WS_W3R + i] = w3[(o * 8 + c) * M_ + w];
        ws[WS_W4R + i] = w4[(o * 8 + c) * M_ + w];
    }
}

// ---------------------------------------------------------------------------
// Kernel 4: power iteration, one wave per batch, no barriers.
// ---------------------------------------------------------------------------
#define GSTR 100
__global__ __launch_bounds__(64) void k_power(float* __restrict__ ws) {
    int b = blockIdx.x, lane = threadIdx.x;
    const float* Gg = ws + WS_G + b * MP * MP;
    __shared__ float Gs[MP * GSTR];   // 38400 B
    __shared__ float vs[MP];

    for (int i = lane; i < MP * MP; i += 64) {
        int m = i / MP, n = i - m * MP;
        Gs[m * GSTR + n] = Gg[i];
    }
    vs[lane] = (lane < M_) ? 1.f : 0.f;
    if (lane < 32) vs[64 + lane] = (64 + lane < M_) ? 1.f : 0.f;

    const float4* g0 = (const float4*)&Gs[lane * GSTR];
    const float4* g1 = (const float4*)&Gs[(64 + (lane & 31)) * GSTR];
    const float4* v4 = (const float4*)vs;

    float r0 = 0.f, r1 = 0.f;
    for (int it = 0; it <= POWER_ITERS; ++it) {
        r0 = 0.f; r1 = 0.f;
#pragma unroll 6
        for (int k = 0; k < MP / 4; ++k) {
            float4 gv = g0[k];
            float4 vv = v4[k];
            r0 = fmaf(gv.x, vv.x, r0);
            r0 = fmaf(gv.y, vv.y, r0);
            r0 = fmaf(gv.z, vv.z, r0);
            r0 = fmaf(gv.w, vv.w, r0);
        }
        if (lane < 32) {
#pragma unroll 6
            for (int k = 0; k < MP / 4; ++k) {
                float4 gv = g1[k];
                float4 vv = v4[k];
                r1 = fmaf(gv.x, vv.x, r1);
                r1 = fmaf(gv.y, vv.y, r1);
                r1 = fmaf(gv.z, vv.z, r1);
                r1 = fmaf(gv.w, vv.w, r1);
            }
        }
        if (it == POWER_ITERS) break;
        float s = r0 * r0 + ((lane < 32) ? r1 * r1 : 0.f);
#pragma unroll
        for (int d = 1; d < 64; d <<= 1) s += __shfl_xor(s, d, 64);
        float inv = 1.f / (sqrtf(s) + 1e-12f);
        vs[lane] = r0 * inv;
        if (lane < 32) vs[64 + lane] = r1 * inv;
    }
    float s = vs[lane] * r0 + ((lane < 32) ? vs[64 + lane] * r1 : 0.f);
#pragma unroll
    for (int d = 1; d < 64; d <<= 1) s += __shfl_xor(s, d, 64);
    if (lane == 0) ws[WS_STEP + b] = 1.f / (s * 1.01f + 1e-8f);
}

// ---------------------------------------------------------------------------
// Kernel 5 (R5): FISTA on MFMA, 6 waves per block (1 m-tile of 16 per wave).
// G hi+lo frags (6 s16x8) in VGPRs. Y (hi/lo bf16) ping-pong in LDS,
// 1 barrier/iter. 9 MFMA in 3 independent chains of 3.
// ---------------------------------------------------------------------------
#define YSTR 104   // bf16 row stride

__global__ __launch_bounds__(384) void k_fista(const float* __restrict__ ws,
                                               float* __restrict__ out) {
    int b = blockIdx.y;
    int j0 = blockIdx.x * 16;
    int tid = threadIdx.x;
    int wid = tid >> 6;          // 0..5 : m-tile index
    int lane = tid & 63;
    int jl = lane & 15;          // j-local (MFMA col)
    int g = lane >> 4;           // 0..3 k-group

    const float* Gg = ws + WS_G + b * MP * MP;
    const float* Cg = ws + WS_C + b * MP * MP;
    float step = ws[WS_STEP + b];

    __shared__ unsigned short Yt[2][2][16 * YSTR];  // [buf][hi/lo][j][n] 13312 B

    for (int i = tid; i < 2 * 2 * 16 * YSTR / 2; i += 384)
        ((unsigned int*)Yt)[i] = 0u;

    // ---- G fragments (hi + lo) in registers: 1 m-tile x 3 n-chunks ----
    s16x8 ghi[3], glo[3];
#pragma unroll
    for (int nc = 0; nc < 3; ++nc) {
        const float* src = Gg + (wid * 16 + jl) * MP + nc * 32 + g * 8;
        s16x8 h, l;
#pragma unroll
        for (int e = 0; e < 8; ++e) {
            float f = src[e];
            unsigned int hb = __float_as_uint(f) & 0xFFFF0000u;
            h[e] = (short)(hb >> 16);
            float lo = f - __uint_as_float(hb);
            l[e] = (short)(__float_as_uint(lo) >> 16);
        }
        ghi[nc] = h;
        glo[nc] = l;
    }

    // ---- C in D-layout; init w/y ----
    float c[4], w[4], y[4];
    {
        const float* src = Cg + (j0 + jl) * MP + wid * 16 + g * 4;
#pragma unroll
        for (int r = 0; r < 4; ++r) {
            c[r] = src[r];
            w[r] = 0.f;
            y[r] = 0.f;
        }
    }

    // read/write LDS bases (per buf, per hi/lo)
    const unsigned short* rb[2][2];
    unsigned short* wb[2][2];
#pragma unroll
    for (int bu = 0; bu < 2; ++bu)
#pragma unroll
        for (int hl = 0; hl < 2; ++hl) {
            rb[bu][hl] = &Yt[bu][hl][jl * YSTR + g * 8];
            wb[bu][hl] = &Yt[bu][hl][jl * YSTR + wid * 16 + g * 4];
        }

    float t = 1.f;
    __syncthreads();

#define FISTA_BODY(CUR, NXT)                                                   \
    {                                                                          \
        s16x8 yh[3], yl[3];                                                    \
        _Pragma("unroll")                                                      \
        for (int nc = 0; nc < 3; ++nc) {                                       \
            yh[nc] = *(const s16x8*)(rb[CUR][0] + nc * 32);                    \
            yl[nc] = *(const s16x8*)(rb[CUR][1] + nc * 32);                    \
        }                                                                      \
        float t1 = 0.5f * (1.f + sqrtf(1.f + 4.f * t * t));                    \
        float coef = (t - 1.f) / t1;                                           \
        t = t1;                                                                \
        f32x4 a1 = {0.f, 0.f, 0.f, 0.f};                                       \
        f32x4 a2 = {0.f, 0.f, 0.f, 0.f};                                       \
        f32x4 a3 = {0.f, 0.f, 0.f, 0.f};                                       \
        _Pragma("unroll")                                                      \
        for (int nc = 0; nc < 3; ++nc)                                         \
            a1 = __builtin_amdgcn_mfma_f32_16x16x32_bf16(ghi[nc], yh[nc], a1, 0, 0, 0); \
        _Pragma("unroll")                                                      \
        for (int nc = 0; nc < 3; ++nc)                                         \
            a2 = __builtin_amdgcn_mfma_f32_16x16x32_bf16(ghi[nc], yl[nc], a2, 0, 0, 0); \
        _Pragma("unroll")                                                      \
        for (int nc = 0; nc < 3; ++nc)                                         \
            a3 = __builtin_amdgcn_mfma_f32_16x16x32_bf16(glo[nc], yh[nc], a3, 0, 0, 0); \
        unsigned int hb[4], lb[4];                                             \
        _Pragma("unroll")                                                      \
        for (int r = 0; r < 4; ++r) {                                          \
            int mg = wid * 16 + g * 4 + r;                                     \
            float gr = (a1[r] + a2[r] + a3[r]) - c[r];                         \
            if (j0 + jl == mg) gr = 0.f;                                       \
            float w1v = fmaxf(fmaf(-step, gr, y[r]), 0.f);                     \
            float yn = fmaf(coef, w1v - w[r], w1v);                            \
            w[r] = w1v;                                                        \
            y[r] = yn;                                                         \
            hb[r] = __float_as_uint(yn) & 0xFFFF0000u;                         \
            float lo = yn - __uint_as_float(hb[r]);                            \
            lb[r] = __float_as_uint(lo);                                       \
        }                                                                      \
        unsigned int h0 = (hb[0] >> 16) | hb[1];                               \
        unsigned int h1 = (hb[2] >> 16) | hb[3];                               \
        unsigned int l0 = (lb[0] >> 16) | (lb[1] & 0xFFFF0000u);               \
        unsigned int l1 = (lb[2] >> 16) | (lb[3] & 0xFFFF0000u);               \
        *(uint2*)(wb[NXT][0]) = make_uint2(h0, h1);                            \
        *(uint2*)(wb[NXT][1]) = make_uint2(l0, l1);                            \
        __syncthreads();                                                       \
    }

    for (int it = 0; it < NNLS_ITERS / 2; ++it) {
        FISTA_BODY(0, 1)
        FISTA_BODY(1, 0)
    }
#undef FISTA_BODY

    // ---- store w -> A[b][j][m] ----
    int jg = j0 + jl;
#pragma unroll
    for (int r = 0; r < 4; ++r) {
        int mg = wid * 16 + g * 4 + r;
        if (jg < M_ && mg < M_)
            out[A_OFF + b * M_ * M_ + jg * M_ + mg] = w[r];
    }
}

// ---------------------------------------------------------------------------
// Kernel 6: BrainNetCNN head, one block per batch.
// ---------------------------------------------------------------------------
__global__ __launch_bounds__(256) void k_cnn(
    const float* __restrict__ out_in, const float* __restrict__ ws,
    const float* __restrict__ c1w, const float* __restrict__ c1b,
    const float* __restrict__ c2w, const float* __restrict__ c2b,
    const float* __restrict__ c3b, const float* __restrict__ c4b,
    const float* __restrict__ e2nw, const float* __restrict__ e2nb,
    const float* __restrict__ n2gw, const float* __restrict__ n2gb,
    const float* __restrict__ d1w, const float* __restrict__ d1b,
    const float* __restrict__ d2w, const float* __restrict__ d2b,
    const float* __restrict__ d3w, const float* __restrict__ d3b,
    float* __restrict__ out) {
    int b = blockIdx.x, tid = threadIdx.x;
    __shared__ float A[M_][92];
    __shared__ float a1[8][92], b1[8][92];
    __shared__ float a2s[16][92], b2s[16][92];
    __shared__ float part[16][92];
    __shared__ float e2n[92], n2g[64], h1[128], h2[12];

    const float* Ag = out_in + A_OFF + b * M_ * M_;
    for (int i = tid; i < M_ * M_; i += 256) A[i / M_][i % M_] = Ag[i];
    __syncthreads();

    for (int q = tid; q < 8 * M_; q += 256) {
        int o = q & 7, h = q >> 3;
        float s = c1b[o];
#pragma unroll 2
        for (int wI = 0; wI < M_; ++wI) s = fmaf(A[h][wI], c1w[o * M_ + wI], s);
        a1[o][h] = s;
    }
    for (int q = tid; q < 8 * M_; q += 256) {
        int o = q & 7, wI = q >> 3;
        float s = c2b[o];
#pragma unroll 2
        for (int h = 0; h < M_; ++h) s = fmaf(A[h][wI], c2w[o * M_ + h], s);
        b1[o][wI] = s;
    }
    __syncthreads();

    const float4* w3r4 = (const float4*)(ws + WS_W3R);
    const float4* w4r4 = (const float4*)(ws + WS_W4R);
    for (int q = tid; q < 720; q += 256) {
        if (q < 360) {
            int oq = q & 3, h = q >> 2;
            float4 acc = make_float4(c3b[4 * oq], c3b[4 * oq + 1],
                                     c3b[4 * oq + 2], c3b[4 * oq + 3]);
#pragma unroll
            for (int ci = 0; ci < 8; ++ci) {
                float av = a1[ci][h];
                for (int wI = 0; wI < M_; ++wI) {
                    float o1v = leaky(av + b1[ci][wI]);
                    float4 wv = w3r4[(ci * M_ + wI) * 4 + oq];
                    acc.x = fmaf(o1v, wv.x, acc.x);
                    acc.y = fmaf(o1v, wv.y, acc.y);
                    acc.z = fmaf(o1v, wv.z, acc.z);
                    acc.w = fmaf(o1v, wv.w, acc.w);
                }
            }
            a2s[4 * oq + 0][h] = acc.x;
            a2s[4 * oq + 1][h] = acc.y;
            a2s[4 * oq + 2][h] = acc.z;
            a2s[4 * oq + 3][h] = acc.w;
        } else {
            int q2 = q - 360;
            int oq = q2 & 3, wI = q2 >> 2;
            float4 acc = make_float4(c4b[4 * oq], c4b[4 * oq + 1],
                                     c4b[4 * oq + 2], c4b[4 * oq + 3]);
#pragma unroll
            for (int ci = 0; ci < 8; ++ci) {
                float bv = b1[ci][wI];
                for (int h = 0; h < M_; ++h) {
                    float o1v = leaky(a1[ci][h] + bv);
                    float4 wv = w4r4[(ci * M_ + h) * 4 + oq];
                    acc.x = fmaf(o1v, wv.x, acc.x);
                    acc.y = fmaf(o1v, wv.y, acc.y);
                    acc.z = fmaf(o1v, wv.z, acc.z);
                    acc.w = fmaf(o1v, wv.w, acc.w);
                }
            }
            b2s[4 * oq + 0][wI] = acc.x;
            b2s[4 * oq + 1][wI] = acc.y;
            b2s[4 * oq + 2][wI] = acc.z;
            b2s[4 * oq + 3][wI] = acc.w;
        }
    }
    __syncthreads();

    for (int q = tid; q < 16 * M_; q += 256) {
        int ci = q & 15, h = q >> 4;
        float av = a2s[ci][h];
        float s = 0.f;
        for (int wI = 0; wI < M_; ++wI)
            s = fmaf(leaky(av + b2s[ci][wI]), e2nw[ci * M_ + wI], s);
        part[ci][h] = s;
    }
    __syncthreads();
    if (tid < M_) {
        float s = e2nb[0];
#pragma unroll
        for (int ci = 0; ci < 16; ++ci) s += part[ci][tid];
        e2n[tid] = leaky(s);
    }
    __syncthreads();
    if (tid < 64) {
        float s = n2gb[tid];
        for (int h = 0; h < M_; ++h) s = fmaf(e2n[h], n2gw[tid * M_ + h], s);
        n2g[tid] = leaky(s);
    }
    __syncthreads();
    if (tid < 128) {
        float s = d1b[tid];
        for (int k = 0; k < 64; ++k) s = fmaf(n2g[k], d1w[tid * 64 + k], s);
        h1[tid] = leaky(s);
    }
    __syncthreads();
    if (tid < 10) {
        float s = d2b[tid];
        for (int k = 0; k < 128; ++k) s = fmaf(h1[k], d2w[tid * 128 + k], s);
        h2[tid] = leaky(s);
    }
    __syncthreads();
    if (tid < 2) {
        float s = d3b[tid];
        for (int k = 0; k < 10; ++k) s = fmaf(h2[k], d3w[tid * 10 + k], s);
        out[CLS_OFF + b * 2 + tid] = leaky(s);
    }
}

// ---------------------------------------------------------------------------
extern "C" void kernel_launch(void* const* d_in, const int* in_sizes, int n_in,
                              void* d_out, int out_size, void* d_ws, size_t ws_size,
                              hipStream_t stream) {
    const float* x0 = (const float*)d_in[0];
    const float* rawx = (const float*)d_in[1];
    const float* c1w = (const float*)d_in[2];
    const float* c1b = (const float*)d_in[3];
    const float* c2w = (const float*)d_in[4];
    const float* c2b = (const float*)d_in[5];
    const float* c3w = (const float*)d_in[6];
    const float* c3b = (const float*)d_in[7];
    const float* c4w = (const float*)d_in[8];
    const float* c4b = (const float*)d_in[9];
    const float* e2nw = (const float*)d_in[10];
    const float* e2nb = (const float*)d_in[11];
    const float* n2gw = (const float*)d_in[12];
    const float* n2gb = (const float*)d_in[13];
    const float* d1w = (const float*)d_in[14];
    const float* d1b = (const float*)d_in[15];
    const float* d2w = (const float*)d_in[16];
    const float* d2b = (const float*)d_in[17];
    const float* d3w = (const float*)d_in[18];
    const float* d3b = (const float*)d_in[19];

    float* out = (float*)d_out;
    float* ws = (float*)d_ws;

    hipLaunchKernelGGL(k_gc, dim3(B_, 2), dim3(256), 0, stream, x0, rawx, ws, out);
    hipLaunchKernelGGL(k_prepack, dim3(2), dim3(256), 0, stream, c3w, c4w, ws);
    hipLaunchKernelGGL(k_power, dim3(B_), dim3(64), 0, stream, ws);
    hipLaunchKernelGGL(k_fista, dim3(MP / 16, B_), dim3(384), 0, stream, ws, out);
    hipLaunchKernelGGL(k_cnn, dim3(B_), dim3(256), 0, stream, out, ws,
                       c1w, c1b, c2w, c2b, c3b, c4b, e2nw, e2nb,
                       n2gw, n2gb, d1w, d1b, d2w, d2b, d3w, d3b, out);
}